// Round 1
// baseline (166.230 us; speedup 1.0000x reference)
//
#include <hip/hip_runtime.h>
#include <hip/hip_bf16.h>
#include <stdint.h>

#define T_DIM 2048
#define C_DIM 1024
#define H_DIM 16
#define D_HEAD 64
#define N_QKV 3072
#define CQ 0.18033688011112042f   // log2(e)/8

typedef __bf16 bf16;
typedef __bf16 bf16x8 __attribute__((ext_vector_type(8)));
typedef __bf16 bf16x4 __attribute__((ext_vector_type(4)));
typedef __bf16 bf16x2 __attribute__((ext_vector_type(2)));
typedef float f32x4 __attribute__((ext_vector_type(4)));
typedef short s16x4 __attribute__((ext_vector_type(4)));

__device__ __forceinline__ void lds_load16(const void* g, void* l) {
    __builtin_amdgcn_global_load_lds(
        (const __attribute__((address_space(1))) void*)g,
        (__attribute__((address_space(3))) void*)l, 16, 0, 0);
}

__device__ __forceinline__ f32x4 mfma16(bf16x4 a, bf16x4 b, f32x4 c) {
#if __has_builtin(__builtin_amdgcn_mfma_f32_16x16x16_bf16)
    return __builtin_amdgcn_mfma_f32_16x16x16_bf16(a, b, c, 0, 0, 0);
#elif __has_builtin(__builtin_amdgcn_mfma_f32_16x16x16bf16_1k)
    union { bf16x4 v; s16x4 s; } ua, ub;
    ua.v = a; ub.v = b;
    return __builtin_amdgcn_mfma_f32_16x16x16bf16_1k(ua.s, ub.s, c, 0, 0, 0);
#else
    asm volatile("v_mfma_f32_16x16x16_bf16 %0, %1, %2, %0"
                 : "+v"(c) : "v"(a), "v"(b));
    return c;
#endif
}

// ---- merged prep: blocks 0..1023 cast x; blocks 1024..5119 transpose both weights ----
__global__ void prep_kernel(const float* __restrict__ x, bf16* __restrict__ xb,
                            const float* __restrict__ Wq, bf16* __restrict__ WqT,
                            const float* __restrict__ Wp, bf16* __restrict__ WpT) {
    __shared__ float tile[32][33];
    int bid = blockIdx.x;
    int t = threadIdx.x;
    if (bid < 1024) {
        int i = (bid * 256 + t) * 8;
        float4 a = *(const float4*)(x + i);
        float4 b = *(const float4*)(x + i + 4);
        bf16x8 o;
        o[0] = (bf16)a.x; o[1] = (bf16)a.y; o[2] = (bf16)a.z; o[3] = (bf16)a.w;
        o[4] = (bf16)b.x; o[5] = (bf16)b.y; o[6] = (bf16)b.z; o[7] = (bf16)b.w;
        *(bf16x8*)(xb + i) = o;
        return;
    }
    bid -= 1024;
    const float* in; bf16* out; int N, nb, kb;
    if (bid < 3072) { in = Wq; out = WqT; N = N_QKV; nb = (bid % 96) * 32; kb = (bid / 96) * 32; }
    else { bid -= 3072; in = Wp; out = WpT; N = C_DIM; nb = (bid % 32) * 32; kb = (bid / 32) * 32; }
    int r = t >> 3, c4 = (t & 7) * 4;
    float4 v = *(const float4*)(in + (size_t)(kb + r) * N + nb + c4);
    tile[r][c4 + 0] = v.x; tile[r][c4 + 1] = v.y;
    tile[r][c4 + 2] = v.z; tile[r][c4 + 3] = v.w;
    __syncthreads();
    bf16x4 ov;
    ov[0] = (bf16)tile[c4 + 0][r]; ov[1] = (bf16)tile[c4 + 1][r];
    ov[2] = (bf16)tile[c4 + 2][r]; ov[3] = (bf16)tile[c4 + 3][r];
    *(bf16x4*)(out + (size_t)(nb + r) * C_DIM + kb + c4) = ov;
}

// ---------------- QKV GEMM 128x64, BK=64, pure DMA staging, XCD-swizzled ----------------
__global__ __launch_bounds__(256, 3) void qkv_gemm_kernel(
    const bf16* __restrict__ A, const bf16* __restrict__ Bt,
    const float* __restrict__ bias, bf16* __restrict__ qkv)
{
    __shared__ __align__(16) bf16 As[2][128 * 32];
    __shared__ __align__(16) bf16 Bs[2][64 * 32];
    const int bid = blockIdx.x;
    const int xcd = bid & 7, slot = bid >> 3;            // slot 0..95
    const int rowBase = (slot / 6) * 128;
    const int colBase = (xcd * 6 + (slot % 6)) * 64;
    const int tid = threadIdx.x, lane = tid & 63, w = tid >> 6;
    const int lo16 = lane & 15, quad = lane >> 4;
    const int wm = (w & 1) * 64, wn = (w >> 1) * 32;

    const bf16* ga = A  + (size_t)(rowBase + w * 16 + (lane >> 2)) * C_DIM + (lane & 3) * 8;
    const bf16* gb = Bt + (size_t)(colBase + w * 16 + (lane >> 2)) * C_DIM + (lane & 3) * 8;

    f32x4 acc[4][2] = {};

    for (int k0 = 0; k0 < C_DIM; k0 += 64) {
        __syncthreads();
        #pragma unroll
        for (int p = 0; p < 2; ++p) {
            lds_load16(ga + k0 + p * 32, &As[p][(w * 16) * 32]);
            lds_load16(ga + (size_t)64 * C_DIM + k0 + p * 32, &As[p][(64 + w * 16) * 32]);
            lds_load16(gb + k0 + p * 32, &Bs[p][(w * 16) * 32]);
        }
        __syncthreads();
        #pragma unroll
        for (int p = 0; p < 2; ++p) {
            bf16x8 af[4], bfr[2];
            #pragma unroll
            for (int mi = 0; mi < 4; ++mi) af[mi]  = *(const bf16x8*)&As[p][(wm + mi * 16 + lo16) * 32 + quad * 8];
            #pragma unroll
            for (int ni = 0; ni < 2; ++ni) bfr[ni] = *(const bf16x8*)&Bs[p][(wn + ni * 16 + lo16) * 32 + quad * 8];
            #pragma unroll
            for (int mi = 0; mi < 4; ++mi)
                #pragma unroll
                for (int ni = 0; ni < 2; ++ni)
                    acc[mi][ni] = __builtin_amdgcn_mfma_f32_16x16x32_bf16(af[mi], bfr[ni], acc[mi][ni], 0, 0, 0);
        }
    }

    const float scale = (colBase < C_DIM) ? CQ : 1.0f;   // Q region prescale
    #pragma unroll
    for (int ni = 0; ni < 2; ++ni) {
        int col = colBase + wn + ni * 16 + lo16;
        float bv = bias[col];
        #pragma unroll
        for (int mi = 0; mi < 4; ++mi) {
            int row0 = rowBase + wm + mi * 16 + quad * 4;
            #pragma unroll
            for (int r = 0; r < 4; ++r)
                qkv[(size_t)(row0 + r) * N_QKV + col] = (bf16)((acc[mi][ni][r] + bv) * scale);
        }
    }
}

// ---------------- flash attention v9: double-buffered V slice, deep prefetch ----------------
// 512 blocks x 512 threads (8 waves). xcd=bid&7 runs heads {2*xcd, 2*xcd+1} (KV L2-resident).
// v9 change vs v8: wave-private V tile in LDS is DOUBLE-buffered. Schedule per iter:
//   issue K(k+1) -> QK mfma -> ds_read V_k (written a FULL iter ago) -> ds_write V_(k+1)
//   (global loads got a full iter of flight) -> issue V(k+2) gather -> exp2 -> PV.
// Removes the same-iteration vmcnt->ds_write->ds_read chain that serialized v8.
// Buffer index pinned at compile time by manual 2x unroll. setprio(1) around MFMA clusters.
#define NKT (T_DIM / 128)

#define FLASH_STEP(KT, RB, WB)                                                        \
    {                                                                                 \
        bf16x8 nkf0 = kf0, nkf1 = kf1;                                                \
        if ((KT) + 1 < NKT) {                                                         \
            const bf16* kp = kfb + (size_t)((KT) + 1) * 128 * N_QKV;                  \
            nkf0 = *(const bf16x8*)(kp);                                              \
            nkf1 = *(const bf16x8*)(kp + 32);                                         \
        }                                                                             \
        f32x4 st[4];                                                                  \
        __builtin_amdgcn_s_setprio(1);                                                \
        _Pragma("unroll")                                                             \
        for (int nq = 0; nq < 4; ++nq) {                                              \
            f32x4 z = {};                                                             \
            z = __builtin_amdgcn_mfma_f32_16x16x32_bf16(kf0, qf[nq][0], z, 0, 0, 0);  \
            st[nq] = __builtin_amdgcn_mfma_f32_16x16x32_bf16(kf1, qf[nq][1], z, 0, 0, 0); \
        }                                                                             \
        __builtin_amdgcn_s_setprio(0);                                                \
        bf16x4 vf[4];                                                                 \
        _Pragma("unroll")                                                             \
        for (int mi = 0; mi < 4; ++mi)                                                \
            vf[mi] = *(const bf16x4*)(vrd##RB + mi * 16 * 38);                        \
        if ((KT) + 1 < NKT) {                                                         \
            union { bf16x8 v; unsigned short us[8]; } p0, p1;                         \
            _Pragma("unroll")                                                         \
            for (int i = 0; i < 8; ++i) { p0.us[i] = vreg[i]; p1.us[i] = vreg[8 + i]; } \
            *(bf16x8*)(vwr##WB)     = p0.v;                                           \
            *(bf16x8*)(vwr##WB + 8) = p1.v;                                           \
            if ((KT) + 2 < NKT) {                                                     \
                _Pragma("unroll")                                                     \
                for (int i = 0; i < 16; ++i)                                          \
                    vreg[i] = vb16[(size_t)(((KT) + 2) * 128 + w * 16 + i) * N_QKV + lane]; \
            }                                                                         \
        }                                                                             \
        bf16x4 pb[4];                                                                 \
        _Pragma("unroll")                                                             \
        for (int nq = 0; nq < 4; ++nq)                                                \
            _Pragma("unroll")                                                         \
            for (int r = 0; r < 4; ++r) {                                             \
                float p = __builtin_amdgcn_exp2f(st[nq][r]);                          \
                l_acc[nq] += p;                                                       \
                pb[nq][r] = (bf16)p;                                                  \
            }                                                                         \
        __builtin_amdgcn_s_setprio(1);                                                \
        _Pragma("unroll")                                                             \
        for (int mi = 0; mi < 4; ++mi)                                                \
            _Pragma("unroll")                                                         \
            for (int nq = 0; nq < 4; ++nq)                                            \
                o_t[mi][nq] = mfma16(vf[mi], pb[nq], o_t[mi][nq]);                    \
        __builtin_amdgcn_s_setprio(0);                                                \
        kf0 = nkf0; kf1 = nkf1;                                                       \
    }

__global__ __launch_bounds__(512, 2) void flash_kernel(
    const bf16* __restrict__ qkv,    // [T][3C]
    bf16* __restrict__ y)            // [T][C]
{
    __shared__ union {
        __align__(16) bf16 Vt[2][4][64][38];    // [buf][w>>1][d][(w&1)*16 + s']
        float Ored[8][16][66];                  // [wave][d_local][q]
    } u;
    __shared__ float lred[8][64];

    const int bid = blockIdx.x;
    const int xcd = bid & 7, slot = bid >> 3;   // slot 0..63
    const int h = xcd * 2 + (slot & 1);
    const int qb = slot >> 1;                   // 0..31
    const int tid  = threadIdx.x;
    const int lane = tid & 63, w = tid >> 6;    // w in 0..7
    const int lo16 = lane & 15, quad = lane >> 4;

    bf16x8 qf[4][2];
    #pragma unroll
    for (int nq = 0; nq < 4; ++nq)
        #pragma unroll
        for (int dk = 0; dk < 2; ++dk)
            qf[nq][dk] = *(const bf16x8*)(qkv + (size_t)(qb * 64 + nq * 16 + lo16) * N_QKV
                                          + h * D_HEAD + dk * 32 + quad * 8);

    f32x4 o_t[4][4] = {};
    float l_acc[4] = {};

    const bf16* kfb = qkv + (size_t)(w * 16 + lo16) * N_QKV + C_DIM + h * D_HEAD + quad * 8;
    const unsigned short* vb16 = (const unsigned short*)(qkv + 2 * C_DIM + h * D_HEAD);

    // wave-private LDS pointers (read: fragment base; write: per-lane d column)
    const bf16* vrd0 = &u.Vt[0][w >> 1][lo16][(w & 1) * 16 + quad * 4];
    const bf16* vrd1 = &u.Vt[1][w >> 1][lo16][(w & 1) * 16 + quad * 4];
    bf16* vwr0 = &u.Vt[0][w >> 1][lane][(w & 1) * 16];
    bf16* vwr1 = &u.Vt[1][w >> 1][lane][(w & 1) * 16];

    // ---- prologue: V0 -> Vt[0]; V1 in flight; K0 in flight ----
    unsigned short vreg[16];
    #pragma unroll
    for (int i = 0; i < 16; ++i)
        vreg[i] = vb16[(size_t)(w * 16 + i) * N_QKV + lane];
    bf16x8 kf0 = *(const bf16x8*)(kfb);
    bf16x8 kf1 = *(const bf16x8*)(kfb + 32);
    {
        union { bf16x8 v; unsigned short us[8]; } p0, p1;
        #pragma unroll
        for (int i = 0; i < 8; ++i) { p0.us[i] = vreg[i]; p1.us[i] = vreg[8 + i]; }
        *(bf16x8*)(vwr0)     = p0.v;
        *(bf16x8*)(vwr0 + 8) = p1.v;
        #pragma unroll
        for (int i = 0; i < 16; ++i)
            vreg[i] = vb16[(size_t)(128 + w * 16 + i) * N_QKV + lane];
    }

    for (int kt = 0; kt < NKT; kt += 2) {
        FLASH_STEP(kt,     0, 1);
        FLASH_STEP(kt + 1, 1, 0);
    }

    #pragma unroll
    for (int nq = 0; nq < 4; ++nq) {
        l_acc[nq] += __shfl_xor(l_acc[nq], 16);
        l_acc[nq] += __shfl_xor(l_acc[nq], 32);
        if (quad == 0) lred[w][nq * 16 + lo16] = l_acc[nq];
    }

    const int q8 = tid >> 3, dh = tid & 7;
    float linv = 0.f;
    #pragma unroll
    for (int mi = 0; mi < 4; ++mi) {
        __syncthreads();
        #pragma unroll
        for (int nq = 0; nq < 4; ++nq)
            #pragma unroll
            for (int r = 0; r < 4; ++r)
                u.Ored[w][quad * 4 + r][nq * 16 + lo16] = o_t[mi][nq][r];
        __syncthreads();
        if (mi == 0) {
            float ls = 0.f;
            #pragma unroll
            for (int j = 0; j < 8; ++j) ls += lred[j][q8];
            linv = 1.0f / ls;
        }
        bf16x2 ov;
        #pragma unroll
        for (int dj = 0; dj < 2; ++dj) {
            int d = dh * 2 + dj;
            float s = 0.f;
            #pragma unroll
            for (int j = 0; j < 8; ++j) s += u.Ored[j][d][q8];
            ov[dj] = (bf16)(s * linv);
        }
        *(bf16x2*)&y[(size_t)(qb * 64 + q8) * C_DIM + h * D_HEAD + mi * 16 + dh * 2] = ov;
    }
}

// ---------------- proj GEMM 64x64, BK=64, pure DMA staging, XCD-swizzled ----------------
__global__ __launch_bounds__(256, 4) void proj_gemm_kernel(
    const bf16* __restrict__ A, const bf16* __restrict__ Bt,
    const float* __restrict__ bias, float* __restrict__ out)
{
    __shared__ __align__(16) bf16 As[2][64 * 32];
    __shared__ __align__(16) bf16 Bs[2][64 * 32];
    const int bid = blockIdx.x;
    const int xcd = bid & 7, slot = bid >> 3;            // slot 0..63
    const int colBase = (xcd * 2 + (slot & 1)) * 64;
    const int rowBase = (slot >> 1) * 64;
    const int tid = threadIdx.x, lane = tid & 63, w = tid >> 6;
    const int lo16 = lane & 15, quad = lane >> 4;
    const int wm = (w & 1) * 32, wn = (w >> 1) * 32;

    const bf16* ga = A  + (size_t)(rowBase + w * 16 + (lane >> 2)) * C_DIM + (lane & 3) * 8;
    const bf16* gb = Bt + (size_t)(colBase + w * 16 + (lane >> 2)) * C_DIM + (lane & 3) * 8;

    f32x4 acc[2][2] = {};

    for (int k0 = 0; k0 < C_DIM; k0 += 64) {
        __syncthreads();
        #pragma unroll
        for (int p = 0; p < 2; ++p) {
            lds_load16(ga + k0 + p * 32, &As[p][(w * 16) * 32]);
            lds_load16(gb + k0 + p * 32, &Bs[p][(w * 16) * 32]);
        }
        __syncthreads();
        #pragma unroll
        for (int p = 0; p < 2; ++p) {
            bf16x8 af[2], bfr[2];
            #pragma unroll
            for (int mi = 0; mi < 2; ++mi) af[mi]  = *(const bf16x8*)&As[p][(wm + mi * 16 + lo16) * 32 + quad * 8];
            #pragma unroll
            for (int ni = 0; ni < 2; ++ni) bfr[ni] = *(const bf16x8*)&Bs[p][(wn + ni * 16 + lo16) * 32 + quad * 8];
            #pragma unroll
            for (int mi = 0; mi < 2; ++mi)
                #pragma unroll
                for (int ni = 0; ni < 2; ++ni)
                    acc[mi][ni] = __builtin_amdgcn_mfma_f32_16x16x32_bf16(af[mi], bfr[ni], acc[mi][ni], 0, 0, 0);
        }
    }

    #pragma unroll
    for (int ni = 0; ni < 2; ++ni) {
        int col = colBase + wn + ni * 16 + lo16;
        float bv = bias[col];
        #pragma unroll
        for (int mi = 0; mi < 2; ++mi) {
            int row0 = rowBase + wm + mi * 16 + quad * 4;
            #pragma unroll
            for (int r = 0; r < 4; ++r)
                out[(size_t)(row0 + r) * C_DIM + col] = acc[mi][ni][r] + bv;
        }
    }
}

extern "C" void kernel_launch(void* const* d_in, const int* in_sizes, int n_in,
                              void* d_out, int out_size, void* d_ws, size_t ws_size,
                              hipStream_t stream) {
    const float* x      = (const float*)d_in[0];
    const float* W_qkv  = (const float*)d_in[1];
    const float* b_qkv  = (const float*)d_in[2];
    const float* W_proj = (const float*)d_in[3];
    const float* b_proj = (const float*)d_in[4];
    float* out = (float*)d_out;

    char* ws = (char*)d_ws;
    bf16* xb      = (bf16*)(ws);                 // [0,4) MB
    bf16* Wqkv_t  = (bf16*)(ws + (4  << 20));    // [4,10) MB
    bf16* Wproj_t = (bf16*)(ws + (10 << 20));    // [10,12) MB
    bf16* qkv_bf  = (bf16*)(ws + (12 << 20));    // [12,24) MB  interleaved [T][3072], Q prescaled
    bf16* yb      = (bf16*)(ws + (24 << 20));    // [24,28) MB
    
    prep_kernel<<<5120, 256, 0, stream>>>(x, xb, W_qkv, Wqkv_t, W_proj, Wproj_t);

    qkv_gemm_kernel<<<768, 256, 0, stream>>>(xb, Wqkv_t, b_qkv, qkv_bf);

    flash_kernel<<<512, 512, 0, stream>>>(qkv_bf, yb);

    proj_gemm_kernel<<<512, 256, 0, stream>>>(yb, Wproj_t, b_proj, out);
}

// Round 2
// 148.785 us; speedup vs baseline: 1.1173x; 1.1173x over previous
//
#include <hip/hip_runtime.h>
#include <hip/hip_bf16.h>
#include <stdint.h>

#define T_DIM 2048
#define C_DIM 1024
#define H_DIM 16
#define D_HEAD 64
#define N_QKV 3072
#define CQ 0.18033688011112042f   // log2(e)/8

typedef __bf16 bf16;
typedef __bf16 bf16x8 __attribute__((ext_vector_type(8)));
typedef __bf16 bf16x4 __attribute__((ext_vector_type(4)));
typedef __bf16 bf16x2 __attribute__((ext_vector_type(2)));
typedef float f32x4 __attribute__((ext_vector_type(4)));
typedef short s16x4 __attribute__((ext_vector_type(4)));

__device__ __forceinline__ void lds_load16(const void* g, void* l) {
    __builtin_amdgcn_global_load_lds(
        (const __attribute__((address_space(1))) void*)g,
        (__attribute__((address_space(3))) void*)l, 16, 0, 0);
}

__device__ __forceinline__ f32x4 mfma16(bf16x4 a, bf16x4 b, f32x4 c) {
#if __has_builtin(__builtin_amdgcn_mfma_f32_16x16x16_bf16)
    return __builtin_amdgcn_mfma_f32_16x16x16_bf16(a, b, c, 0, 0, 0);
#elif __has_builtin(__builtin_amdgcn_mfma_f32_16x16x16bf16_1k)
    union { bf16x4 v; s16x4 s; } ua, ub;
    ua.v = a; ub.v = b;
    return __builtin_amdgcn_mfma_f32_16x16x16bf16_1k(ua.s, ub.s, c, 0, 0, 0);
#else
    asm volatile("v_mfma_f32_16x16x16_bf16 %0, %1, %2, %0"
                 : "+v"(c) : "v"(a), "v"(b));
    return c;
#endif
}

// ---- merged prep: blocks 0..1023 cast x; blocks 1024..5119 transpose both weights ----
__global__ void prep_kernel(const float* __restrict__ x, bf16* __restrict__ xb,
                            const float* __restrict__ Wq, bf16* __restrict__ WqT,
                            const float* __restrict__ Wp, bf16* __restrict__ WpT) {
    __shared__ float tile[32][33];
    int bid = blockIdx.x;
    int t = threadIdx.x;
    if (bid < 1024) {
        int i = (bid * 256 + t) * 8;
        float4 a = *(const float4*)(x + i);
        float4 b = *(const float4*)(x + i + 4);
        bf16x8 o;
        o[0] = (bf16)a.x; o[1] = (bf16)a.y; o[2] = (bf16)a.z; o[3] = (bf16)a.w;
        o[4] = (bf16)b.x; o[5] = (bf16)b.y; o[6] = (bf16)b.z; o[7] = (bf16)b.w;
        *(bf16x8*)(xb + i) = o;
        return;
    }
    bid -= 1024;
    const float* in; bf16* out; int N, nb, kb;
    if (bid < 3072) { in = Wq; out = WqT; N = N_QKV; nb = (bid % 96) * 32; kb = (bid / 96) * 32; }
    else { bid -= 3072; in = Wp; out = WpT; N = C_DIM; nb = (bid % 32) * 32; kb = (bid / 32) * 32; }
    int r = t >> 3, c4 = (t & 7) * 4;
    float4 v = *(const float4*)(in + (size_t)(kb + r) * N + nb + c4);
    tile[r][c4 + 0] = v.x; tile[r][c4 + 1] = v.y;
    tile[r][c4 + 2] = v.z; tile[r][c4 + 3] = v.w;
    __syncthreads();
    bf16x4 ov;
    ov[0] = (bf16)tile[c4 + 0][r]; ov[1] = (bf16)tile[c4 + 1][r];
    ov[2] = (bf16)tile[c4 + 2][r]; ov[3] = (bf16)tile[c4 + 3][r];
    *(bf16x4*)(out + (size_t)(nb + r) * C_DIM + kb + c4) = ov;
}

// ---------------- QKV GEMM 128x64, BK=64, double-buffered DMA pipeline ----------------
// v2: T3-minimum 2-phase. Issue next K-step's global_load_lds into buf^1 BEFORE
// computing buf, then raw s_waitcnt vmcnt(0) + s_barrier (one barrier per K-step).
// Loads overlap the whole ds_read+MFMA phase instead of stalling between two barriers.
#define QKV_STAGE(BUF, K0) do {                                              \
    lds_load16(ga + (K0),                  &As[BUF][0][(w * 16) * 32]);      \
    lds_load16(ga + (K0) + 32,             &As[BUF][1][(w * 16) * 32]);      \
    lds_load16(ga + (size_t)64 * C_DIM + (K0),      &As[BUF][0][(64 + w * 16) * 32]); \
    lds_load16(ga + (size_t)64 * C_DIM + (K0) + 32, &As[BUF][1][(64 + w * 16) * 32]); \
    lds_load16(gb + (K0),                  &Bs[BUF][0][(w * 16) * 32]);      \
    lds_load16(gb + (K0) + 32,             &Bs[BUF][1][(w * 16) * 32]);      \
} while (0)

#define QKV_COMPUTE(BUF) do {                                                \
    _Pragma("unroll")                                                        \
    for (int p = 0; p < 2; ++p) {                                            \
        bf16x8 af[4], bfr[2];                                                \
        _Pragma("unroll")                                                    \
        for (int mi = 0; mi < 4; ++mi) af[mi]  = *(const bf16x8*)&As[BUF][p][(wm + mi * 16 + lo16) * 32 + quad * 8]; \
        _Pragma("unroll")                                                    \
        for (int ni = 0; ni < 2; ++ni) bfr[ni] = *(const bf16x8*)&Bs[BUF][p][(wn + ni * 16 + lo16) * 32 + quad * 8]; \
        _Pragma("unroll")                                                    \
        for (int mi = 0; mi < 4; ++mi)                                       \
            _Pragma("unroll")                                                \
            for (int ni = 0; ni < 2; ++ni)                                   \
                acc[mi][ni] = __builtin_amdgcn_mfma_f32_16x16x32_bf16(af[mi], bfr[ni], acc[mi][ni], 0, 0, 0); \
    }                                                                        \
} while (0)

#define WAIT_AND_BARRIER() do {                                              \
    asm volatile("s_waitcnt vmcnt(0)" ::: "memory");                         \
    __builtin_amdgcn_s_barrier();                                            \
} while (0)

__global__ __launch_bounds__(256, 3) void qkv_gemm_kernel(
    const bf16* __restrict__ A, const bf16* __restrict__ Bt,
    const float* __restrict__ bias, bf16* __restrict__ qkv)
{
    __shared__ __align__(16) bf16 As[2][2][128 * 32];
    __shared__ __align__(16) bf16 Bs[2][2][64 * 32];
    const int bid = blockIdx.x;
    const int xcd = bid & 7, slot = bid >> 3;            // slot 0..95
    const int rowBase = (slot / 6) * 128;
    const int colBase = (xcd * 6 + (slot % 6)) * 64;
    const int tid = threadIdx.x, lane = tid & 63, w = tid >> 6;
    const int lo16 = lane & 15, quad = lane >> 4;
    const int wm = (w & 1) * 64, wn = (w >> 1) * 32;

    const bf16* ga = A  + (size_t)(rowBase + w * 16 + (lane >> 2)) * C_DIM + (lane & 3) * 8;
    const bf16* gb = Bt + (size_t)(colBase + w * 16 + (lane >> 2)) * C_DIM + (lane & 3) * 8;

    f32x4 acc[4][2] = {};

    QKV_STAGE(0, 0);
    WAIT_AND_BARRIER();

    for (int k0 = 0; k0 < C_DIM; k0 += 128) {
        // A: stage k0+64 -> buf1 (always valid: k0 max 896), compute buf0
        QKV_STAGE(1, k0 + 64);
        QKV_COMPUTE(0);
        WAIT_AND_BARRIER();
        // B: stage k0+128 -> buf0 (guarded), compute buf1
        if (k0 + 128 < C_DIM) QKV_STAGE(0, k0 + 128);
        QKV_COMPUTE(1);
        WAIT_AND_BARRIER();
    }

    const float scale = (colBase < C_DIM) ? CQ : 1.0f;   // Q region prescale
    #pragma unroll
    for (int ni = 0; ni < 2; ++ni) {
        int col = colBase + wn + ni * 16 + lo16;
        float bv = bias[col];
        #pragma unroll
        for (int mi = 0; mi < 4; ++mi) {
            int row0 = rowBase + wm + mi * 16 + quad * 4;
            #pragma unroll
            for (int r = 0; r < 4; ++r)
                qkv[(size_t)(row0 + r) * N_QKV + col] = (bf16)((acc[mi][ni][r] + bv) * scale);
        }
    }
}

// ---------------- flash attention v8 (reverted) + setprio around PV cluster ----------------
// 512 blocks x 512 threads (8 waves). xcd=bid&7 runs ONLY heads {2*xcd, 2*xcd+1}:
// KV streams from L3 once per XCD. K frags direct-global (prefetched), V gathered into
// wave-private LDS slice (in-order DS, no in-loop barriers), Q prescaled -> bare exp2.
__global__ __launch_bounds__(512, 2) void flash_kernel(
    const bf16* __restrict__ qkv,    // [T][3C]
    bf16* __restrict__ y)            // [T][C]
{
    __shared__ union {
        __align__(16) bf16 Vt[4][64][38];       // [w>>1][d][(w&1)*16 + s']
        float Ored[8][16][66];                  // [wave][d_local][q]
    } u;
    __shared__ float lred[8][64];

    const int bid = blockIdx.x;
    const int xcd = bid & 7, slot = bid >> 3;   // slot 0..63
    const int h = xcd * 2 + (slot & 1);
    const int qb = slot >> 1;                   // 0..31
    const int tid  = threadIdx.x;
    const int lane = tid & 63, w = tid >> 6;    // w in 0..7
    const int lo16 = lane & 15, quad = lane >> 4;

    bf16x8 qf[4][2];
    #pragma unroll
    for (int nq = 0; nq < 4; ++nq)
        #pragma unroll
        for (int dk = 0; dk < 2; ++dk)
            qf[nq][dk] = *(const bf16x8*)(qkv + (size_t)(qb * 64 + nq * 16 + lo16) * N_QKV
                                          + h * D_HEAD + dk * 32 + quad * 8);

    f32x4 o_t[4][4] = {};
    float l_acc[4] = {};

    const bf16* kfb = qkv + (size_t)(w * 16 + lo16) * N_QKV + C_DIM + h * D_HEAD + quad * 8;
    const unsigned short* vb16 = (const unsigned short*)(qkv + 2 * C_DIM + h * D_HEAD);

    bf16x8 kf0 = *(const bf16x8*)(kfb);
    bf16x8 kf1 = *(const bf16x8*)(kfb + 32);
    unsigned short vreg[16];
    #pragma unroll
    for (int i = 0; i < 16; ++i)
        vreg[i] = vb16[(size_t)(w * 16 + i) * N_QKV + lane];

    bf16* vdst = &u.Vt[w >> 1][lane][(w & 1) * 16];

    for (int kt = 0; kt < T_DIM / 128; ++kt) {
        union { bf16x8 v; unsigned short us[8]; } p0, p1;
        #pragma unroll
        for (int i = 0; i < 8; ++i) { p0.us[i] = vreg[i]; p1.us[i] = vreg[8 + i]; }
        *(bf16x8*)vdst       = p0.v;
        *(bf16x8*)(vdst + 8) = p1.v;

        bf16x8 nkf0 = kf0, nkf1 = kf1;
        if (kt + 1 < T_DIM / 128) {
            const bf16* kp = kfb + (size_t)(kt + 1) * 128 * N_QKV;
            nkf0 = *(const bf16x8*)(kp);
            nkf1 = *(const bf16x8*)(kp + 32);
            #pragma unroll
            for (int i = 0; i < 16; ++i)
                vreg[i] = vb16[(size_t)((kt + 1) * 128 + w * 16 + i) * N_QKV + lane];
        }

        f32x4 st[4];
        #pragma unroll
        for (int nq = 0; nq < 4; ++nq) {
            f32x4 z = {};
            z = __builtin_amdgcn_mfma_f32_16x16x32_bf16(kf0, qf[nq][0], z, 0, 0, 0);
            st[nq] = __builtin_amdgcn_mfma_f32_16x16x32_bf16(kf1, qf[nq][1], z, 0, 0, 0);
        }

        bf16x4 pb[4];
        #pragma unroll
        for (int nq = 0; nq < 4; ++nq)
            #pragma unroll
            for (int r = 0; r < 4; ++r) {
                float p = __builtin_amdgcn_exp2f(st[nq][r]);
                l_acc[nq] += p;
                pb[nq][r] = (bf16)p;
            }

        bf16x4 vf[4];
        #pragma unroll
        for (int mi = 0; mi < 4; ++mi)
            vf[mi] = *(const bf16x4*)&u.Vt[w >> 1][mi * 16 + lo16][(w & 1) * 16 + quad * 4];

        __builtin_amdgcn_s_setprio(1);
        #pragma unroll
        for (int mi = 0; mi < 4; ++mi)
            #pragma unroll
            for (int nq = 0; nq < 4; ++nq)
                o_t[mi][nq] = mfma16(vf[mi], pb[nq], o_t[mi][nq]);
        __builtin_amdgcn_s_setprio(0);

        kf0 = nkf0; kf1 = nkf1;
    }

    #pragma unroll
    for (int nq = 0; nq < 4; ++nq) {
        l_acc[nq] += __shfl_xor(l_acc[nq], 16);
        l_acc[nq] += __shfl_xor(l_acc[nq], 32);
        if (quad == 0) lred[w][nq * 16 + lo16] = l_acc[nq];
    }

    const int q8 = tid >> 3, dh = tid & 7;
    float linv = 0.f;
    #pragma unroll
    for (int mi = 0; mi < 4; ++mi) {
        __syncthreads();
        #pragma unroll
        for (int nq = 0; nq < 4; ++nq)
            #pragma unroll
            for (int r = 0; r < 4; ++r)
                u.Ored[w][quad * 4 + r][nq * 16 + lo16] = o_t[mi][nq][r];
        __syncthreads();
        if (mi == 0) {
            float ls = 0.f;
            #pragma unroll
            for (int j = 0; j < 8; ++j) ls += lred[j][q8];
            linv = 1.0f / ls;
        }
        bf16x2 ov;
        #pragma unroll
        for (int dj = 0; dj < 2; ++dj) {
            int d = dh * 2 + dj;
            float s = 0.f;
            #pragma unroll
            for (int j = 0; j < 8; ++j) s += u.Ored[j][d][q8];
            ov[dj] = (bf16)(s * linv);
        }
        *(bf16x2*)&y[(size_t)(qb * 64 + q8) * C_DIM + h * D_HEAD + mi * 16 + dh * 2] = ov;
    }
}

// ---------------- proj GEMM 64x64, BK=64, double-buffered DMA pipeline ----------------
#define PROJ_STAGE(BUF, K0) do {                                             \
    lds_load16(ga + (K0),      &As[BUF][0][(w * 16) * 32]);                  \
    lds_load16(ga + (K0) + 32, &As[BUF][1][(w * 16) * 32]);                  \
    lds_load16(gb + (K0),      &Bs[BUF][0][(w * 16) * 32]);                  \
    lds_load16(gb + (K0) + 32, &Bs[BUF][1][(w * 16) * 32]);                  \
} while (0)

#define PROJ_COMPUTE(BUF) do {                                               \
    _Pragma("unroll")                                                        \
    for (int p = 0; p < 2; ++p) {                                            \
        bf16x8 af[2], bfr[2];                                                \
        _Pragma("unroll")                                                    \
        for (int mi = 0; mi < 2; ++mi) af[mi]  = *(const bf16x8*)&As[BUF][p][(wm + mi * 16 + lo16) * 32 + quad * 8]; \
        _Pragma("unroll")                                                    \
        for (int ni = 0; ni < 2; ++ni) bfr[ni] = *(const bf16x8*)&Bs[BUF][p][(wn + ni * 16 + lo16) * 32 + quad * 8]; \
        _Pragma("unroll")                                                    \
        for (int mi = 0; mi < 2; ++mi)                                       \
            _Pragma("unroll")                                                \
            for (int ni = 0; ni < 2; ++ni)                                   \
                acc[mi][ni] = __builtin_amdgcn_mfma_f32_16x16x32_bf16(af[mi], bfr[ni], acc[mi][ni], 0, 0, 0); \
    }                                                                        \
} while (0)

__global__ __launch_bounds__(256, 4) void proj_gemm_kernel(
    const bf16* __restrict__ A, const bf16* __restrict__ Bt,
    const float* __restrict__ bias, float* __restrict__ out)
{
    __shared__ __align__(16) bf16 As[2][2][64 * 32];
    __shared__ __align__(16) bf16 Bs[2][2][64 * 32];
    const int bid = blockIdx.x;
    const int xcd = bid & 7, slot = bid >> 3;            // slot 0..63
    const int colBase = (xcd * 2 + (slot & 1)) * 64;
    const int rowBase = (slot >> 1) * 64;
    const int tid = threadIdx.x, lane = tid & 63, w = tid >> 6;
    const int lo16 = lane & 15, quad = lane >> 4;
    const int wm = (w & 1) * 32, wn = (w >> 1) * 32;

    const bf16* ga = A  + (size_t)(rowBase + w * 16 + (lane >> 2)) * C_DIM + (lane & 3) * 8;
    const bf16* gb = Bt + (size_t)(colBase + w * 16 + (lane >> 2)) * C_DIM + (lane & 3) * 8;

    f32x4 acc[2][2] = {};

    PROJ_STAGE(0, 0);
    WAIT_AND_BARRIER();

    for (int k0 = 0; k0 < C_DIM; k0 += 128) {
        PROJ_STAGE(1, k0 + 64);
        PROJ_COMPUTE(0);
        WAIT_AND_BARRIER();
        if (k0 + 128 < C_DIM) PROJ_STAGE(0, k0 + 128);
        PROJ_COMPUTE(1);
        WAIT_AND_BARRIER();
    }

    #pragma unroll
    for (int ni = 0; ni < 2; ++ni) {
        int col = colBase + wn + ni * 16 + lo16;
        float bv = bias[col];
        #pragma unroll
        for (int mi = 0; mi < 2; ++mi) {
            int row0 = rowBase + wm + mi * 16 + quad * 4;
            #pragma unroll
            for (int r = 0; r < 4; ++r)
                out[(size_t)(row0 + r) * C_DIM + col] = acc[mi][ni][r] + bv;
        }
    }
}

extern "C" void kernel_launch(void* const* d_in, const int* in_sizes, int n_in,
                              void* d_out, int out_size, void* d_ws, size_t ws_size,
                              hipStream_t stream) {
    const float* x      = (const float*)d_in[0];
    const float* W_qkv  = (const float*)d_in[1];
    const float* b_qkv  = (const float*)d_in[2];
    const float* W_proj = (const float*)d_in[3];
    const float* b_proj = (const float*)d_in[4];
    float* out = (float*)d_out;

    char* ws = (char*)d_ws;
    bf16* xb      = (bf16*)(ws);                 // [0,4) MB
    bf16* Wqkv_t  = (bf16*)(ws + (4  << 20));    // [4,10) MB
    bf16* Wproj_t = (bf16*)(ws + (10 << 20));    // [10,12) MB
    bf16* qkv_bf  = (bf16*)(ws + (12 << 20));    // [12,24) MB  interleaved [T][3072], Q prescaled
    bf16* yb      = (bf16*)(ws + (24 << 20));    // [24,28) MB

    prep_kernel<<<5120, 256, 0, stream>>>(x, xb, W_qkv, Wqkv_t, W_proj, Wproj_t);

    qkv_gemm_kernel<<<768, 256, 0, stream>>>(xb, Wqkv_t, b_qkv, qkv_bf);

    flash_kernel<<<512, 512, 0, stream>>>(qkv_bf, yb);

    proj_gemm_kernel<<<512, 256, 0, stream>>>(yb, Wproj_t, b_proj, out);
}

// Round 3
// 145.752 us; speedup vs baseline: 1.1405x; 1.0208x over previous
//
#include <hip/hip_runtime.h>
#include <hip/hip_bf16.h>
#include <stdint.h>

#define T_DIM 2048
#define C_DIM 1024
#define H_DIM 16
#define D_HEAD 64
#define N_QKV 3072
#define CQ 0.18033688011112042f   // log2(e)/8

typedef __bf16 bf16;
typedef __bf16 bf16x8 __attribute__((ext_vector_type(8)));
typedef __bf16 bf16x4 __attribute__((ext_vector_type(4)));
typedef __bf16 bf16x2 __attribute__((ext_vector_type(2)));
typedef float f32x4 __attribute__((ext_vector_type(4)));
typedef short s16x4 __attribute__((ext_vector_type(4)));

__device__ __forceinline__ void lds_load16(const void* g, void* l) {
    __builtin_amdgcn_global_load_lds(
        (const __attribute__((address_space(1))) void*)g,
        (__attribute__((address_space(3))) void*)l, 16, 0, 0);
}

__device__ __forceinline__ f32x4 mfma16(bf16x4 a, bf16x4 b, f32x4 c) {
#if __has_builtin(__builtin_amdgcn_mfma_f32_16x16x16_bf16)
    return __builtin_amdgcn_mfma_f32_16x16x16_bf16(a, b, c, 0, 0, 0);
#elif __has_builtin(__builtin_amdgcn_mfma_f32_16x16x16bf16_1k)
    union { bf16x4 v; s16x4 s; } ua, ub;
    ua.v = a; ub.v = b;
    return __builtin_amdgcn_mfma_f32_16x16x16bf16_1k(ua.s, ub.s, c, 0, 0, 0);
#else
    asm volatile("v_mfma_f32_16x16x16_bf16 %0, %1, %2, %0"
                 : "+v"(c) : "v"(a), "v"(b));
    return c;
#endif
}

// ---- merged prep: blocks 0..1023 cast x; blocks 1024..5119 transpose both weights ----
__global__ void prep_kernel(const float* __restrict__ x, bf16* __restrict__ xb,
                            const float* __restrict__ Wq, bf16* __restrict__ WqT,
                            const float* __restrict__ Wp, bf16* __restrict__ WpT) {
    __shared__ float tile[32][33];
    int bid = blockIdx.x;
    int t = threadIdx.x;
    if (bid < 1024) {
        int i = (bid * 256 + t) * 8;
        float4 a = *(const float4*)(x + i);
        float4 b = *(const float4*)(x + i + 4);
        bf16x8 o;
        o[0] = (bf16)a.x; o[1] = (bf16)a.y; o[2] = (bf16)a.z; o[3] = (bf16)a.w;
        o[4] = (bf16)b.x; o[5] = (bf16)b.y; o[6] = (bf16)b.z; o[7] = (bf16)b.w;
        *(bf16x8*)(xb + i) = o;
        return;
    }
    bid -= 1024;
    const float* in; bf16* out; int N, nb, kb;
    if (bid < 3072) { in = Wq; out = WqT; N = N_QKV; nb = (bid % 96) * 32; kb = (bid / 96) * 32; }
    else { bid -= 3072; in = Wp; out = WpT; N = C_DIM; nb = (bid % 32) * 32; kb = (bid / 32) * 32; }
    int r = t >> 3, c4 = (t & 7) * 4;
    float4 v = *(const float4*)(in + (size_t)(kb + r) * N + nb + c4);
    tile[r][c4 + 0] = v.x; tile[r][c4 + 1] = v.y;
    tile[r][c4 + 2] = v.z; tile[r][c4 + 3] = v.w;
    __syncthreads();
    bf16x4 ov;
    ov[0] = (bf16)tile[c4 + 0][r]; ov[1] = (bf16)tile[c4 + 1][r];
    ov[2] = (bf16)tile[c4 + 2][r]; ov[3] = (bf16)tile[c4 + 3][r];
    *(bf16x4*)(out + (size_t)(nb + r) * C_DIM + kb + c4) = ov;
}

// ---------------- QKV GEMM 128x128, BK=64, 2-phase DMA pipeline, XCD-swizzled ----------------
// v3: full m97-class tile. 32 MFMA/wave per K-step vs 16, staged bytes/FLOP x0.7.
// 384 blocks (16 row x 24 col), xcd owns 3 col-panels (B panel 768KB -> L2-resident).
// LDS 64KB -> 2 blocks/CU (8 waves).
#define QKV_STAGE(BUF, K0) do {                                                      \
    lds_load16(ga + (K0),                            &As[BUF][0][(w * 16) * 32]);    \
    lds_load16(ga + (K0) + 32,                       &As[BUF][1][(w * 16) * 32]);    \
    lds_load16(ga + (size_t)64 * C_DIM + (K0),       &As[BUF][0][(64 + w * 16) * 32]); \
    lds_load16(ga + (size_t)64 * C_DIM + (K0) + 32,  &As[BUF][1][(64 + w * 16) * 32]); \
    lds_load16(gb + (K0),                            &Bs[BUF][0][(w * 16) * 32]);    \
    lds_load16(gb + (K0) + 32,                       &Bs[BUF][1][(w * 16) * 32]);    \
    lds_load16(gb + (size_t)64 * C_DIM + (K0),       &Bs[BUF][0][(64 + w * 16) * 32]); \
    lds_load16(gb + (size_t)64 * C_DIM + (K0) + 32,  &Bs[BUF][1][(64 + w * 16) * 32]); \
} while (0)

#define QKV_COMPUTE(BUF) do {                                                \
    _Pragma("unroll")                                                        \
    for (int p = 0; p < 2; ++p) {                                            \
        bf16x8 af[4], bfr[4];                                                \
        _Pragma("unroll")                                                    \
        for (int mi = 0; mi < 4; ++mi) af[mi]  = *(const bf16x8*)&As[BUF][p][(wm + mi * 16 + lo16) * 32 + quad * 8]; \
        _Pragma("unroll")                                                    \
        for (int ni = 0; ni < 4; ++ni) bfr[ni] = *(const bf16x8*)&Bs[BUF][p][(wn + ni * 16 + lo16) * 32 + quad * 8]; \
        _Pragma("unroll")                                                    \
        for (int mi = 0; mi < 4; ++mi)                                       \
            _Pragma("unroll")                                                \
            for (int ni = 0; ni < 4; ++ni)                                   \
                acc[mi][ni] = __builtin_amdgcn_mfma_f32_16x16x32_bf16(af[mi], bfr[ni], acc[mi][ni], 0, 0, 0); \
    }                                                                        \
} while (0)

#define WAIT_AND_BARRIER() do {                                              \
    asm volatile("s_waitcnt vmcnt(0)" ::: "memory");                         \
    __builtin_amdgcn_s_barrier();                                            \
} while (0)

__global__ __launch_bounds__(256, 2) void qkv_gemm_kernel(
    const bf16* __restrict__ A, const bf16* __restrict__ Bt,
    const float* __restrict__ bias, bf16* __restrict__ qkv)
{
    __shared__ __align__(16) bf16 As[2][2][128 * 32];
    __shared__ __align__(16) bf16 Bs[2][2][128 * 32];
    const int bid = blockIdx.x;
    const int xcd = bid & 7, slot = bid >> 3;            // slot 0..47
    const int rowBase = (slot / 3) * 128;                // 16 row-blocks
    const int colBase = (xcd * 3 + (slot % 3)) * 128;    // 24 col-blocks
    const int tid = threadIdx.x, lane = tid & 63, w = tid >> 6;
    const int lo16 = lane & 15, quad = lane >> 4;
    const int wm = (w & 1) * 64, wn = (w >> 1) * 64;

    const bf16* ga = A  + (size_t)(rowBase + w * 16 + (lane >> 2)) * C_DIM + (lane & 3) * 8;
    const bf16* gb = Bt + (size_t)(colBase + w * 16 + (lane >> 2)) * C_DIM + (lane & 3) * 8;

    f32x4 acc[4][4] = {};

    QKV_STAGE(0, 0);
    WAIT_AND_BARRIER();

    for (int k0 = 0; k0 < C_DIM; k0 += 128) {
        QKV_STAGE(1, k0 + 64);
        QKV_COMPUTE(0);
        WAIT_AND_BARRIER();
        if (k0 + 128 < C_DIM) QKV_STAGE(0, k0 + 128);
        QKV_COMPUTE(1);
        WAIT_AND_BARRIER();
    }

    const float scale = (colBase < C_DIM) ? CQ : 1.0f;   // Q region prescale (128 | 1024)
    #pragma unroll
    for (int ni = 0; ni < 4; ++ni) {
        int col = colBase + wn + ni * 16 + lo16;
        float bv = bias[col];
        #pragma unroll
        for (int mi = 0; mi < 4; ++mi) {
            int row0 = rowBase + wm + mi * 16 + quad * 4;
            #pragma unroll
            for (int r = 0; r < 4; ++r)
                qkv[(size_t)(row0 + r) * N_QKV + col] = (bf16)((acc[mi][ni][r] + bv) * scale);
        }
    }
}

// ---------------- flash attention v10: v8 + l-via-MFMA + early vf reads ----------------
// 512 blocks x 512 threads (8 waves). xcd=bid&7 runs ONLY heads {2*xcd, 2*xcd+1}.
// v10: (a) l accumulated by 4 extra mfma16 with A=ones (D[i][q]=sum_k P[k][q]) ->
// kills 16 serial v_add_f32/kt and the epilogue shuffles; (b) vf ds_reads hoisted
// right after the ds_writes (in-order DS => RAW-safe) so PV's lgkm wait is hidden
// under prefetch-issue + QK + exp2.
__global__ __launch_bounds__(512, 2) void flash_kernel(
    const bf16* __restrict__ qkv,    // [T][3C]
    bf16* __restrict__ y)            // [T][C]
{
    __shared__ union {
        __align__(16) bf16 Vt[4][64][38];       // [w>>1][d][(w&1)*16 + s']
        float Ored[8][16][66];                  // [wave][d_local][q]
    } u;
    __shared__ float lred[8][64];

    const int bid = blockIdx.x;
    const int xcd = bid & 7, slot = bid >> 3;   // slot 0..63
    const int h = xcd * 2 + (slot & 1);
    const int qb = slot >> 1;                   // 0..31
    const int tid  = threadIdx.x;
    const int lane = tid & 63, w = tid >> 6;    // w in 0..7
    const int lo16 = lane & 15, quad = lane >> 4;

    bf16x8 qf[4][2];
    #pragma unroll
    for (int nq = 0; nq < 4; ++nq)
        #pragma unroll
        for (int dk = 0; dk < 2; ++dk)
            qf[nq][dk] = *(const bf16x8*)(qkv + (size_t)(qb * 64 + nq * 16 + lo16) * N_QKV
                                          + h * D_HEAD + dk * 32 + quad * 8);

    f32x4 o_t[4][4] = {};
    f32x4 o_l[4] = {};                          // l accumulated via MFMA ones-trick
    bf16x4 ones1;
    ones1[0] = (bf16)1.0f; ones1[1] = (bf16)1.0f; ones1[2] = (bf16)1.0f; ones1[3] = (bf16)1.0f;

    const bf16* kfb = qkv + (size_t)(w * 16 + lo16) * N_QKV + C_DIM + h * D_HEAD + quad * 8;
    const unsigned short* vb16 = (const unsigned short*)(qkv + 2 * C_DIM + h * D_HEAD);

    bf16x8 kf0 = *(const bf16x8*)(kfb);
    bf16x8 kf1 = *(const bf16x8*)(kfb + 32);
    unsigned short vreg[16];
    #pragma unroll
    for (int i = 0; i < 16; ++i)
        vreg[i] = vb16[(size_t)(w * 16 + i) * N_QKV + lane];

    bf16* vdst = &u.Vt[w >> 1][lane][(w & 1) * 16];

    for (int kt = 0; kt < T_DIM / 128; ++kt) {
        union { bf16x8 v; unsigned short us[8]; } p0, p1;
        #pragma unroll
        for (int i = 0; i < 8; ++i) { p0.us[i] = vreg[i]; p1.us[i] = vreg[8 + i]; }
        *(bf16x8*)vdst       = p0.v;
        *(bf16x8*)(vdst + 8) = p1.v;

        // early V-fragment reads: in-order DS makes these RAW-safe; their latency
        // hides under the prefetch issue + QK MFMA + exp2 below.
        bf16x4 vf[4];
        #pragma unroll
        for (int mi = 0; mi < 4; ++mi)
            vf[mi] = *(const bf16x4*)&u.Vt[w >> 1][mi * 16 + lo16][(w & 1) * 16 + quad * 4];

        bf16x8 nkf0 = kf0, nkf1 = kf1;
        if (kt + 1 < T_DIM / 128) {
            const bf16* kp = kfb + (size_t)(kt + 1) * 128 * N_QKV;
            nkf0 = *(const bf16x8*)(kp);
            nkf1 = *(const bf16x8*)(kp + 32);
            #pragma unroll
            for (int i = 0; i < 16; ++i)
                vreg[i] = vb16[(size_t)((kt + 1) * 128 + w * 16 + i) * N_QKV + lane];
        }

        f32x4 st[4];
        #pragma unroll
        for (int nq = 0; nq < 4; ++nq) {
            f32x4 z = {};
            z = __builtin_amdgcn_mfma_f32_16x16x32_bf16(kf0, qf[nq][0], z, 0, 0, 0);
            st[nq] = __builtin_amdgcn_mfma_f32_16x16x32_bf16(kf1, qf[nq][1], z, 0, 0, 0);
        }

        bf16x4 pb[4];
        #pragma unroll
        for (int nq = 0; nq < 4; ++nq)
            #pragma unroll
            for (int r = 0; r < 4; ++r)
                pb[nq][r] = (bf16)__builtin_amdgcn_exp2f(st[nq][r]);

        __builtin_amdgcn_s_setprio(1);
        #pragma unroll
        for (int nq = 0; nq < 4; ++nq)
            o_l[nq] = mfma16(ones1, pb[nq], o_l[nq]);
        #pragma unroll
        for (int mi = 0; mi < 4; ++mi)
            #pragma unroll
            for (int nq = 0; nq < 4; ++nq)
                o_t[mi][nq] = mfma16(vf[mi], pb[nq], o_t[mi][nq]);
        __builtin_amdgcn_s_setprio(0);

        kf0 = nkf0; kf1 = nkf1;
    }

    // o_l[nq][r] already holds sum over this wave's 16 keys for q = nq*16+lo16
    // (all r identical) -> no cross-lane reduce needed.
    #pragma unroll
    for (int nq = 0; nq < 4; ++nq)
        if (quad == 0) lred[w][nq * 16 + lo16] = o_l[nq][0];

    const int q8 = tid >> 3, dh = tid & 7;
    float linv = 0.f;
    #pragma unroll
    for (int mi = 0; mi < 4; ++mi) {
        __syncthreads();
        #pragma unroll
        for (int nq = 0; nq < 4; ++nq)
            #pragma unroll
            for (int r = 0; r < 4; ++r)
                u.Ored[w][quad * 4 + r][nq * 16 + lo16] = o_t[mi][nq][r];
        __syncthreads();
        if (mi == 0) {
            float ls = 0.f;
            #pragma unroll
            for (int j = 0; j < 8; ++j) ls += lred[j][q8];
            linv = 1.0f / ls;
        }
        bf16x2 ov;
        #pragma unroll
        for (int dj = 0; dj < 2; ++dj) {
            int d = dh * 2 + dj;
            float s = 0.f;
            #pragma unroll
            for (int j = 0; j < 8; ++j) s += u.Ored[j][d][q8];
            ov[dj] = (bf16)(s * linv);
        }
        *(bf16x2*)&y[(size_t)(qb * 64 + q8) * C_DIM + h * D_HEAD + mi * 16 + dh * 2] = ov;
    }
}

// ---------------- proj GEMM 64x64, BK=64, 2-phase DMA pipeline (unchanged control) ----------------
#define PROJ_STAGE(BUF, K0) do {                                             \
    lds_load16(ga + (K0),      &As[BUF][0][(w * 16) * 32]);                  \
    lds_load16(ga + (K0) + 32, &As[BUF][1][(w * 16) * 32]);                  \
    lds_load16(gb + (K0),      &Bs[BUF][0][(w * 16) * 32]);                  \
    lds_load16(gb + (K0) + 32, &Bs[BUF][1][(w * 16) * 32]);                  \
} while (0)

#define PROJ_COMPUTE(BUF) do {                                               \
    _Pragma("unroll")                                                        \
    for (int p = 0; p < 2; ++p) {                                            \
        bf16x8 af[2], bfr[2];                                                \
        _Pragma("unroll")                                                    \
        for (int mi = 0; mi < 2; ++mi) af[mi]  = *(const bf16x8*)&As[BUF][p][(wm + mi * 16 + lo16) * 32 + quad * 8]; \
        _Pragma("unroll")                                                    \
        for (int ni = 0; ni < 2; ++ni) bfr[ni] = *(const bf16x8*)&Bs[BUF][p][(wn + ni * 16 + lo16) * 32 + quad * 8]; \
        _Pragma("unroll")                                                    \
        for (int mi = 0; mi < 2; ++mi)                                       \
            _Pragma("unroll")                                                \
            for (int ni = 0; ni < 2; ++ni)                                   \
                acc[mi][ni] = __builtin_amdgcn_mfma_f32_16x16x32_bf16(af[mi], bfr[ni], acc[mi][ni], 0, 0, 0); \
    }                                                                        \
} while (0)

__global__ __launch_bounds__(256, 4) void proj_gemm_kernel(
    const bf16* __restrict__ A, const bf16* __restrict__ Bt,
    const float* __restrict__ bias, float* __restrict__ out)
{
    __shared__ __align__(16) bf16 As[2][2][64 * 32];
    __shared__ __align__(16) bf16 Bs[2][2][64 * 32];
    const int bid = blockIdx.x;
    const int xcd = bid & 7, slot = bid >> 3;            // slot 0..63
    const int colBase = (xcd * 2 + (slot & 1)) * 64;
    const int rowBase = (slot >> 1) * 64;
    const int tid = threadIdx.x, lane = tid & 63, w = tid >> 6;
    const int lo16 = lane & 15, quad = lane >> 4;
    const int wm = (w & 1) * 32, wn = (w >> 1) * 32;

    const bf16* ga = A  + (size_t)(rowBase + w * 16 + (lane >> 2)) * C_DIM + (lane & 3) * 8;
    const bf16* gb = Bt + (size_t)(colBase + w * 16 + (lane >> 2)) * C_DIM + (lane & 3) * 8;

    f32x4 acc[2][2] = {};

    PROJ_STAGE(0, 0);
    WAIT_AND_BARRIER();

    for (int k0 = 0; k0 < C_DIM; k0 += 128) {
        PROJ_STAGE(1, k0 + 64);
        PROJ_COMPUTE(0);
        WAIT_AND_BARRIER();
        if (k0 + 128 < C_DIM) PROJ_STAGE(0, k0 + 128);
        PROJ_COMPUTE(1);
        WAIT_AND_BARRIER();
    }

    #pragma unroll
    for (int ni = 0; ni < 2; ++ni) {
        int col = colBase + wn + ni * 16 + lo16;
        float bv = bias[col];
        #pragma unroll
        for (int mi = 0; mi < 2; ++mi) {
            int row0 = rowBase + wm + mi * 16 + quad * 4;
            #pragma unroll
            for (int r = 0; r < 4; ++r)
                out[(size_t)(row0 + r) * C_DIM + col] = acc[mi][ni][r] + bv;
        }
    }
}

extern "C" void kernel_launch(void* const* d_in, const int* in_sizes, int n_in,
                              void* d_out, int out_size, void* d_ws, size_t ws_size,
                              hipStream_t stream) {
    const float* x      = (const float*)d_in[0];
    const float* W_qkv  = (const float*)d_in[1];
    const float* b_qkv  = (const float*)d_in[2];
    const float* W_proj = (const float*)d_in[3];
    const float* b_proj = (const float*)d_in[4];
    float* out = (float*)d_out;

    char* ws = (char*)d_ws;
    bf16* xb      = (bf16*)(ws);                 // [0,4) MB
    bf16* Wqkv_t  = (bf16*)(ws + (4  << 20));    // [4,10) MB
    bf16* Wproj_t = (bf16*)(ws + (10 << 20));    // [10,12) MB
    bf16* qkv_bf  = (bf16*)(ws + (12 << 20));    // [12,24) MB  interleaved [T][3072], Q prescaled
    bf16* yb      = (bf16*)(ws + (24 << 20));    // [24,28) MB

    prep_kernel<<<5120, 256, 0, stream>>>(x, xb, W_qkv, Wqkv_t, W_proj, Wproj_t);

    qkv_gemm_kernel<<<384, 256, 0, stream>>>(xb, Wqkv_t, b_qkv, qkv_bf);

    flash_kernel<<<512, 512, 0, stream>>>(qkv_bf, yb);

    proj_gemm_kernel<<<512, 256, 0, stream>>>(yb, Wproj_t, b_proj, out);
}